// Round 1
// baseline (395.070 us; speedup 1.0000x reference)
//
#include <hip/hip_runtime.h>
#include <math.h>

// ---------------------------------------------------------------------------
// TransformerEncoderLayer (prenorm), T=2048, N=4, H=512, heads=8, d_head=64.
// SCALE = 1/(512^64) underflows to 0.0f  =>  softmax(logits*0) is uniform
// => attention output = per-batch mean of V rows. Attention collapses to:
//   mean_h1[b,:]  = (1/T) * sum_t LN1(x)[t,b,:]
//   v_mean[b,:]   = mean_h1[b,:] @ Wv + bv        (Wv = qkv_w[:,1024:1536])
//   c[b,:]        = v_mean[b,:] @ out_w + out_b
//   x2[t,b,:]     = x[t,b,:] + c[b,:]
// Then the FFN dominates:
//   h2 = LN2(x2); f1 = relu(h2@ff1_w + b1); out = x2 + f1@ff2_w + b2
// All fp32 (no fp32 MFMA on CDNA4 -> vector GEMM).
// ---------------------------------------------------------------------------

#define DEVI __device__ __forceinline__

constexpr int T_ = 2048;
constexpr int NB = 4;
constexpr int H  = 512;
constexpr int M  = T_ * NB;      // 8192 rows
constexpr int H3 = 3 * H;        // 1536
constexpr int FF = 2 * H;        // 1024
constexpr float LN_EPS = 1e-5f;

constexpr int NCHUNK = 256;      // K1 grid: 256 blocks, 8 t's per block

// workspace layout (in floats)
constexpr size_t OFF_PART  = 0;                                  // 4*NCHUNK*H
constexpr size_t OFF_MEAN  = OFF_PART + (size_t)4 * NCHUNK * H;  // 2048
constexpr size_t OFF_VMEAN = OFF_MEAN + (size_t)NB * H;          // 2048
constexpr size_t OFF_C     = OFF_VMEAN + (size_t)NB * H;         // 2048
constexpr size_t OFF_H2    = OFF_C + (size_t)NB * H;             // M*H
constexpr size_t OFF_F1    = OFF_H2 + (size_t)M * H;             // M*FF

DEVI float hsum8(const float4& a, const float4& b) {
    return a.x + a.y + a.z + a.w + b.x + b.y + b.z + b.w;
}
DEVI float hsq8(const float4& a, const float4& b) {
    return a.x*a.x + a.y*a.y + a.z*a.z + a.w*a.w +
           b.x*b.x + b.y*b.y + b.z*b.z + b.w*b.w;
}
DEVI float4 ln_apply(const float4& v, float mean, float rs,
                     const float4& g, const float4& b) {
    float4 r;
    r.x = (v.x - mean) * rs * g.x + b.x;
    r.y = (v.y - mean) * rs * g.y + b.y;
    r.z = (v.z - mean) * rs * g.z + b.z;
    r.w = (v.w - mean) * rs * g.w + b.w;
    return r;
}
DEVI void add4(float4& a, const float4& b) {
    a.x += b.x; a.y += b.y; a.z += b.z; a.w += b.w;
}

DEVI void wave_reduce2(float& s, float& q) {
    #pragma unroll
    for (int m = 1; m < 64; m <<= 1) {
        s += __shfl_xor(s, m, 64);
        q += __shfl_xor(q, m, 64);
    }
}

// ---------------------------------------------------------------------------
// K1: per-row LN1, accumulate per-batch partial sums over t.
// Block = 256 threads = 4 waves; wave w handles batch w, 8 consecutive t's.
// partials[b][chunk][0:512]
// ---------------------------------------------------------------------------
__global__ __launch_bounds__(256) void k_ln1_partial(
    const float* __restrict__ x, const float* __restrict__ g,
    const float* __restrict__ be, float* __restrict__ partials)
{
    const int lane = threadIdx.x & 63;
    const int w    = threadIdx.x >> 6;   // wave id == batch id
    const int t0   = blockIdx.x * 8;

    const float4* G4 = (const float4*)g;
    const float4* B4 = (const float4*)be;
    const float4 g0 = G4[lane], g1 = G4[64 + lane];
    const float4 b0 = B4[lane], b1 = B4[64 + lane];

    float4 acc0 = {0, 0, 0, 0}, acc1 = {0, 0, 0, 0};

    for (int i = 0; i < 8; ++i) {
        const int r = (t0 + i) * NB + w;
        const float4* X4 = (const float4*)(x + (size_t)r * H);
        float4 v0 = X4[lane], v1 = X4[64 + lane];
        float s = hsum8(v0, v1);
        float q = hsq8(v0, v1);
        wave_reduce2(s, q);
        const float mean = s * (1.0f / H);
        const float var  = q * (1.0f / H) - mean * mean;
        const float rs   = 1.0f / sqrtf(var + LN_EPS);
        float4 h0 = ln_apply(v0, mean, rs, g0, b0);
        float4 h1 = ln_apply(v1, mean, rs, g1, b1);
        add4(acc0, h0);
        add4(acc1, h1);
    }
    float4* P4 = (float4*)(partials + ((size_t)w * NCHUNK + blockIdx.x) * H);
    P4[lane]      = acc0;
    P4[64 + lane] = acc1;
}

// ---------------------------------------------------------------------------
// K2: reduce partials -> mean_h1[b][e]   (2048 threads)
// ---------------------------------------------------------------------------
__global__ void k_reduce_mean(const float* __restrict__ partials,
                              float* __restrict__ mean_h1)
{
    const int tid = blockIdx.x * blockDim.x + threadIdx.x;   // 0..2047
    const int b = tid >> 9;
    const int e = tid & 511;
    float s = 0.f;
    for (int c = 0; c < NCHUNK; ++c)
        s += partials[((size_t)b * NCHUNK + c) * H + e];
    mean_h1[tid] = s * (1.0f / T_);
}

// ---------------------------------------------------------------------------
// K3: v_mean[b][j] = qkv_b[1024+j] + sum_k mean_h1[b][k]*qkv_w[k][1024+j]
// ---------------------------------------------------------------------------
__global__ void k_vproj(const float* __restrict__ mh,
                        const float* __restrict__ qkv_w,
                        const float* __restrict__ qkv_b,
                        float* __restrict__ vmean)
{
    const int tid = blockIdx.x * blockDim.x + threadIdx.x;   // 0..2047
    const int b = tid >> 9;
    const int j = tid & 511;
    float acc = qkv_b[2 * H + j];
    const float* wv = qkv_w + 2 * H + j;     // stride H3 per k
    const float* m  = mh + (size_t)b * H;
    for (int k = 0; k < H; ++k)
        acc = fmaf(m[k], wv[(size_t)k * H3], acc);
    vmean[tid] = acc;
}

// ---------------------------------------------------------------------------
// K4: c[b][j] = out_b[j] + sum_k v_mean[b][k]*out_w[k][j]
// ---------------------------------------------------------------------------
__global__ void k_oproj(const float* __restrict__ vmean,
                        const float* __restrict__ out_w,
                        const float* __restrict__ out_b,
                        float* __restrict__ cvec)
{
    const int tid = blockIdx.x * blockDim.x + threadIdx.x;   // 0..2047
    const int b = tid >> 9;
    const int j = tid & 511;
    float acc = out_b[j];
    const float* vm = vmean + (size_t)b * H;
    for (int k = 0; k < H; ++k)
        acc = fmaf(vm[k], out_w[(size_t)k * H + j], acc);
    cvec[tid] = acc;
}

// ---------------------------------------------------------------------------
// K5: h2 = LN2(x + c[b]);  one wave per row, 4 rows per block.
// ---------------------------------------------------------------------------
__global__ __launch_bounds__(256) void k_ln2(
    const float* __restrict__ x, const float* __restrict__ cvec,
    const float* __restrict__ g, const float* __restrict__ be,
    float* __restrict__ h2)
{
    const int lane = threadIdx.x & 63;
    const int w    = threadIdx.x >> 6;
    const int r    = blockIdx.x * 4 + w;
    const int b    = r & 3;

    const float4* X4 = (const float4*)(x + (size_t)r * H);
    const float4* C4 = (const float4*)(cvec + (size_t)b * H);
    float4 v0 = X4[lane], v1 = X4[64 + lane];
    add4(v0, C4[lane]);
    add4(v1, C4[64 + lane]);

    float s = hsum8(v0, v1);
    float q = hsq8(v0, v1);
    wave_reduce2(s, q);
    const float mean = s * (1.0f / H);
    const float var  = q * (1.0f / H) - mean * mean;
    const float rs   = 1.0f / sqrtf(var + LN_EPS);

    const float4* G4 = (const float4*)g;
    const float4* B4 = (const float4*)be;
    float4 h0 = ln_apply(v0, mean, rs, G4[lane],      B4[lane]);
    float4 h1 = ln_apply(v1, mean, rs, G4[64 + lane], B4[64 + lane]);

    float4* H4 = (float4*)(h2 + (size_t)r * H);
    H4[lane]      = h0;
    H4[64 + lane] = h1;
}

// ---------------------------------------------------------------------------
// Tiled fp32 GEMM. A[M][K] row-major, B[K][N] row-major.
// MODE 0: C = relu(A@B + bias)         (ff1)
// MODE 1: C = A@B + bias + x + c[b]    (ff2 + residual)
// 256 threads; BK=16; thread tile TM x TN.
// ---------------------------------------------------------------------------
template<int BM, int BN, int TM, int TN, int MODE>
__global__ __launch_bounds__(256) void gemm_kernel(
    const float* __restrict__ A, const float* __restrict__ B,
    const float* __restrict__ bias, const float* __restrict__ resid_x,
    const float* __restrict__ resid_c, float* __restrict__ C,
    const int K, const int N)
{
    constexpr int BK = 16;
    __shared__ float As[BK][BM];
    __shared__ float Bs[BK][BN];

    const int t   = threadIdx.x;
    const int bm0 = blockIdx.x * BM;
    const int bn0 = blockIdx.y * BN;
    const int tx  = t % (BN / TN);
    const int ty  = t / (BN / TN);

    float acc[TM][TN];
    #pragma unroll
    for (int i = 0; i < TM; ++i)
        #pragma unroll
        for (int j = 0; j < TN; ++j) acc[i][j] = 0.f;

    for (int k0 = 0; k0 < K; k0 += BK) {
        // stage A tile (transposed into LDS)
        #pragma unroll
        for (int i = 0; i < BM / 64; ++i) {
            const int p   = t + i * 256;
            const int row = p >> 2;             // 4 float4 per row (BK=16)
            const int kc  = (p & 3) * 4;
            float4 v = *(const float4*)(A + (size_t)(bm0 + row) * K + k0 + kc);
            As[kc + 0][row] = v.x;
            As[kc + 1][row] = v.y;
            As[kc + 2][row] = v.z;
            As[kc + 3][row] = v.w;
        }
        // stage B tile
        #pragma unroll
        for (int i = 0; i < BN / 64; ++i) {
            const int p  = t + i * 256;
            const int kk = p / (BN / 4);
            const int c4 = p % (BN / 4);
            float4 v = *(const float4*)(B + (size_t)(k0 + kk) * N + bn0 + c4 * 4);
            *(float4*)&Bs[kk][c4 * 4] = v;
        }
        __syncthreads();

        #pragma unroll
        for (int kk = 0; kk < BK; ++kk) {
            float a[TM], bb[TN];
            #pragma unroll
            for (int i = 0; i < TM; i += 4)
                *(float4*)&a[i] = *(const float4*)&As[kk][ty * TM + i];
            #pragma unroll
            for (int j = 0; j < TN; j += 4)
                *(float4*)&bb[j] = *(const float4*)&Bs[kk][tx * TN + j];
            #pragma unroll
            for (int i = 0; i < TM; ++i)
                #pragma unroll
                for (int j = 0; j < TN; ++j)
                    acc[i][j] = fmaf(a[i], bb[j], acc[i][j]);
        }
        __syncthreads();
    }

    // epilogue
    #pragma unroll
    for (int i = 0; i < TM; ++i) {
        const int row = bm0 + ty * TM + i;
        #pragma unroll
        for (int j = 0; j < TN; j += 4) {
            const int col = bn0 + tx * TN + j;
            float4 v;
            v.x = acc[i][j + 0];
            v.y = acc[i][j + 1];
            v.z = acc[i][j + 2];
            v.w = acc[i][j + 3];
            const float4 bv = *(const float4*)&bias[col];
            v.x += bv.x; v.y += bv.y; v.z += bv.z; v.w += bv.w;
            if (MODE == 0) {
                v.x = fmaxf(v.x, 0.f);
                v.y = fmaxf(v.y, 0.f);
                v.z = fmaxf(v.z, 0.f);
                v.w = fmaxf(v.w, 0.f);
            } else {
                const float4 xr = *(const float4*)&resid_x[(size_t)row * H + col];
                const float4 cr = *(const float4*)&resid_c[(size_t)(row & 3) * H + col];
                v.x += xr.x + cr.x;
                v.y += xr.y + cr.y;
                v.z += xr.z + cr.z;
                v.w += xr.w + cr.w;
            }
            *(float4*)&C[(size_t)row * N + col] = v;
        }
    }
}

// ---------------------------------------------------------------------------
extern "C" void kernel_launch(void* const* d_in, const int* in_sizes, int n_in,
                              void* d_out, int out_size, void* d_ws, size_t ws_size,
                              hipStream_t stream)
{
    const float* x     = (const float*)d_in[0];
    const float* qkv_w = (const float*)d_in[1];
    const float* qkv_b = (const float*)d_in[2];
    const float* out_w = (const float*)d_in[3];
    const float* out_b = (const float*)d_in[4];
    const float* ln1_g = (const float*)d_in[5];
    const float* ln1_b = (const float*)d_in[6];
    const float* ff1_w = (const float*)d_in[7];
    const float* ff1_b = (const float*)d_in[8];
    const float* ff2_w = (const float*)d_in[9];
    const float* ff2_b = (const float*)d_in[10];
    const float* ln2_g = (const float*)d_in[11];
    const float* ln2_b = (const float*)d_in[12];

    float* out = (float*)d_out;
    float* ws  = (float*)d_ws;

    float* partials = ws + OFF_PART;
    float* mh       = ws + OFF_MEAN;
    float* vmean    = ws + OFF_VMEAN;
    float* cvec     = ws + OFF_C;
    float* h2       = ws + OFF_H2;
    float* f1       = ws + OFF_F1;

    // attention path (collapsed by SCALE==0)
    k_ln1_partial<<<NCHUNK, 256, 0, stream>>>(x, ln1_g, ln1_b, partials);
    k_reduce_mean<<<8, 256, 0, stream>>>(partials, mh);
    k_vproj<<<8, 256, 0, stream>>>(mh, qkv_w, qkv_b, vmean);
    k_oproj<<<8, 256, 0, stream>>>(vmean, out_w, out_b, cvec);

    // x2 = x + c ; h2 = LN2(x2)
    k_ln2<<<M / 4, 256, 0, stream>>>(x, cvec, ln2_g, ln2_b, h2);

    // f1 = relu(h2 @ ff1_w + ff1_b)        [8192,512]@[512,1024]
    dim3 g1(M / 128, FF / 128);
    gemm_kernel<128, 128, 8, 8, 0><<<g1, 256, 0, stream>>>(
        h2, ff1_w, ff1_b, nullptr, nullptr, f1, H, FF);

    // out = x + c + f1 @ ff2_w + ff2_b     [8192,1024]@[1024,512]
    dim3 g2(M / 128, H / 64);
    gemm_kernel<128, 64, 8, 4, 1><<<g2, 256, 0, stream>>>(
        f1, ff2_w, ff2_b, x, cvec, out, FF, H);
}

// Round 2
// 179.521 us; speedup vs baseline: 2.2007x; 2.2007x over previous
//
#include <hip/hip_runtime.h>
#include <math.h>

// ---------------------------------------------------------------------------
// TransformerEncoderLayer (prenorm), T=2048, N=4, H=512.
// SCALE = 1/(512^64) underflows to 0.0f => softmax uniform => attention out =
// per-batch mean of V rows (see round-0 derivation; verified passing).
// This round: FFN GEMMs on bf16 MFMA (16x16x32), weights split bf16 hi+lo
// (2 MFMAs/frag-pair) for near-fp32 weight precision; activations plain bf16.
// ---------------------------------------------------------------------------

#define DEVI __device__ __forceinline__

typedef unsigned short u16;
typedef unsigned int   u32;
using short8 = __attribute__((ext_vector_type(8))) short;
using f32x4  = __attribute__((ext_vector_type(4))) float;

constexpr int T_ = 2048;
constexpr int NB = 4;
constexpr int H  = 512;
constexpr int M  = T_ * NB;      // 8192 rows
constexpr int FF = 2 * H;        // 1024
constexpr float LN_EPS = 1e-5f;
constexpr int NCHUNK = 256;

DEVI u16 f2bf(float f) {
    union { float f; u32 u; } v; v.f = f;
    u32 r = v.u + 0x7FFFu + ((v.u >> 16) & 1u);   // RNE
    return (u16)(r >> 16);
}
DEVI float bf2f(u16 h) {
    union { u32 u; float f; } v; v.u = ((u32)h) << 16; return v.f;
}

DEVI void gload16(const u16* src, u16* lds) {
    __builtin_amdgcn_global_load_lds(
        (const __attribute__((address_space(1))) u32*)src,
        (__attribute__((address_space(3))) u32*)lds, 16, 0, 0);
}

DEVI float hsum8(const float4& a, const float4& b) {
    return a.x + a.y + a.z + a.w + b.x + b.y + b.z + b.w;
}
DEVI float hsq8(const float4& a, const float4& b) {
    return a.x*a.x + a.y*a.y + a.z*a.z + a.w*a.w +
           b.x*b.x + b.y*b.y + b.z*b.z + b.w*b.w;
}
DEVI float4 ln_apply(const float4& v, float mean, float rs,
                     const float4& g, const float4& b) {
    float4 r;
    r.x = (v.x - mean) * rs * g.x + b.x;
    r.y = (v.y - mean) * rs * g.y + b.y;
    r.z = (v.z - mean) * rs * g.z + b.z;
    r.w = (v.w - mean) * rs * g.w + b.w;
    return r;
}
DEVI void add4(float4& a, const float4& b) {
    a.x += b.x; a.y += b.y; a.z += b.z; a.w += b.w;
}
DEVI void wave_reduce2(float& s, float& q) {
    #pragma unroll
    for (int m = 1; m < 64; m <<= 1) {
        s += __shfl_xor(s, m, 64);
        q += __shfl_xor(q, m, 64);
    }
}

// ---------------------------------------------------------------------------
// K1: per-row LN1 + per-batch partial sums over t. 256 blocks x 4 waves.
// ---------------------------------------------------------------------------
__global__ __launch_bounds__(256) void k_ln1_partial(
    const float* __restrict__ x, const float* __restrict__ g,
    const float* __restrict__ be, float* __restrict__ partials)
{
    const int lane = threadIdx.x & 63;
    const int w    = threadIdx.x >> 6;
    const int t0   = blockIdx.x * 8;

    const float4* G4 = (const float4*)g;
    const float4* B4 = (const float4*)be;
    const float4 g0 = G4[lane], g1 = G4[64 + lane];
    const float4 b0 = B4[lane], b1 = B4[64 + lane];

    float4 acc0 = {0, 0, 0, 0}, acc1 = {0, 0, 0, 0};
    for (int i = 0; i < 8; ++i) {
        const int r = (t0 + i) * NB + w;
        const float4* X4 = (const float4*)(x + (size_t)r * H);
        float4 v0 = X4[lane], v1 = X4[64 + lane];
        float s = hsum8(v0, v1);
        float q = hsq8(v0, v1);
        wave_reduce2(s, q);
        const float mean = s * (1.0f / H);
        const float var  = q * (1.0f / H) - mean * mean;
        const float rs   = 1.0f / sqrtf(var + LN_EPS);
        add4(acc0, ln_apply(v0, mean, rs, g0, b0));
        add4(acc1, ln_apply(v1, mean, rs, g1, b1));
    }
    float4* P4 = (float4*)(partials + ((size_t)w * NCHUNK + blockIdx.x) * H);
    P4[lane]      = acc0;
    P4[64 + lane] = acc1;
}

// ---------------------------------------------------------------------------
// K2: reduce partials -> mean_h1[b][e]
// ---------------------------------------------------------------------------
__global__ void k_reduce_mean(const float* __restrict__ partials,
                              float* __restrict__ mean_h1)
{
    const int tid = blockIdx.x * blockDim.x + threadIdx.x;   // 0..2047
    const int b = tid >> 9;
    const int e = tid & 511;
    float s = 0.f;
    for (int c = 0; c < NCHUNK; ++c)
        s += partials[((size_t)b * NCHUNK + c) * H + e];
    mean_h1[tid] = s * (1.0f / T_);
}

// ---------------------------------------------------------------------------
// Wave-per-output GEMV: out[b][j] = bias[j] + dot(vec[b,:], W[:, colofs+j])
// grid 512 blocks x 256 thr = 2048 waves.
// ---------------------------------------------------------------------------
__global__ __launch_bounds__(256) void k_gemv_wave(
    const float* __restrict__ vec, const float* __restrict__ W,
    const float* __restrict__ bias, float* __restrict__ outv,
    const int Kd, const int rowstride, const int colofs)
{
    const int wid  = blockIdx.x * 4 + (threadIdx.x >> 6);  // 0..2047
    const int lane = threadIdx.x & 63;
    const int b = wid >> 9;
    const int j = wid & 511;
    const float* v  = vec + (size_t)b * Kd;
    const float* wc = W + colofs + j;
    float s = 0.f;
    for (int i = 0; i < Kd / 64; ++i) {
        const int k = i * 64 + lane;
        s = fmaf(v[k], wc[(size_t)k * rowstride], s);
    }
    #pragma unroll
    for (int m = 1; m < 64; m <<= 1) s += __shfl_xor(s, m, 64);
    if (lane == 0) outv[wid] = s + bias[j];
}

// ---------------------------------------------------------------------------
// K5: h2 = LN2(x + c[b]) -> bf16
// ---------------------------------------------------------------------------
__global__ __launch_bounds__(256) void k_ln2(
    const float* __restrict__ x, const float* __restrict__ cvec,
    const float* __restrict__ g, const float* __restrict__ be,
    u16* __restrict__ h2bf)
{
    const int lane = threadIdx.x & 63;
    const int w    = threadIdx.x >> 6;
    const int r    = blockIdx.x * 4 + w;
    const int b    = r & 3;

    const float4* X4 = (const float4*)(x + (size_t)r * H);
    const float4* C4 = (const float4*)(cvec + (size_t)b * H);
    float4 v0 = X4[lane], v1 = X4[64 + lane];
    add4(v0, C4[lane]);
    add4(v1, C4[64 + lane]);

    float s = hsum8(v0, v1);
    float q = hsq8(v0, v1);
    wave_reduce2(s, q);
    const float mean = s * (1.0f / H);
    const float var  = q * (1.0f / H) - mean * mean;
    const float rs   = 1.0f / sqrtf(var + LN_EPS);

    const float4* G4 = (const float4*)g;
    const float4* B4 = (const float4*)be;
    float4 h0 = ln_apply(v0, mean, rs, G4[lane],      B4[lane]);
    float4 h1 = ln_apply(v1, mean, rs, G4[64 + lane], B4[64 + lane]);

    u16* row = h2bf + (size_t)r * H;
    *(ushort4*)&row[lane * 4]       = make_ushort4(f2bf(h0.x), f2bf(h0.y), f2bf(h0.z), f2bf(h0.w));
    *(ushort4*)&row[256 + lane * 4] = make_ushort4(f2bf(h1.x), f2bf(h1.y), f2bf(h1.z), f2bf(h1.w));
}

// ---------------------------------------------------------------------------
// Weight transpose + hi/lo split: W [K][N] fp32 -> Whi/Wlo [N][K] bf16.
// grid (K/32, N/32), 256 threads.
// ---------------------------------------------------------------------------
__global__ __launch_bounds__(256) void k_wsplit(
    const float* __restrict__ W, u16* __restrict__ Whi, u16* __restrict__ Wlo,
    const int K, const int N)
{
    __shared__ float tile[32][33];
    const int kt = blockIdx.x * 32, nt = blockIdx.y * 32;
    const int t = threadIdx.x;
    #pragma unroll
    for (int i = 0; i < 4; ++i) {
        const int idx = t + i * 256;
        const int r = idx >> 5, c = idx & 31;
        tile[r][c] = W[(size_t)(kt + r) * N + nt + c];
    }
    __syncthreads();
    #pragma unroll
    for (int i = 0; i < 4; ++i) {
        const int idx = t + i * 256;
        const int r = idx >> 5, c = idx & 31;      // r = n-local, c = k-local
        const float v = tile[c][r];
        const u16 hi = f2bf(v);
        const u16 lo = f2bf(v - bf2f(hi));
        const size_t o = (size_t)(nt + r) * K + kt + c;
        Whi[o] = hi;
        Wlo[o] = lo;
    }
}

// ---------------------------------------------------------------------------
// bf16 MFMA GEMM, m97-style (global_load_lds w16, BK=32, 2-barrier loop).
// A [Mrows][K] bf16 row-major. B given TRANSPOSED: Bhi/Blo [N][K] bf16.
// 256 threads = 4 waves (2x2), wave tile (BM/2)x(BN/2), 16x16x32 frags.
// MODE 0: outbf = bf16(relu(A@B + bias))
// MODE 1: outf  = A@B + bias + resid_x + resid_c[row&3]   (N == H)
// ---------------------------------------------------------------------------
template<int BM, int BN, int MODE>
__global__ __launch_bounds__(256) void gemm_bf16(
    const u16* __restrict__ Abf, const u16* __restrict__ Bhi,
    const u16* __restrict__ Blo, const float* __restrict__ bias,
    const float* __restrict__ resid_x, const float* __restrict__ resid_c,
    float* __restrict__ outf, u16* __restrict__ outbf,
    const int K, const int N)
{
    constexpr int BK = 32;
    constexpr int WM = BM / 2, WN = BN / 2;
    constexpr int FM = WM / 16, FN = WN / 16;
    __shared__ alignas(16) u16 As[BM * BK];
    __shared__ alignas(16) u16 Bh[BN * BK];
    __shared__ alignas(16) u16 Bl[BN * BK];

    const int t    = threadIdx.x;
    const int lane = t & 63, w = t >> 6;
    const int wr = w >> 1, wc = w & 1;
    const int lr = lane & 15, lk = lane >> 4;
    const int bm0 = blockIdx.x * BM, bn0 = blockIdx.y * BN;

    f32x4 acc[FM][FN];
    #pragma unroll
    for (int i = 0; i < FM; ++i)
        #pragma unroll
        for (int j = 0; j < FN; ++j)
            acc[i][j] = (f32x4){0.f, 0.f, 0.f, 0.f};

    for (int k0 = 0; k0 < K; k0 += BK) {
        __syncthreads();
        #pragma unroll
        for (int c = 0; c < BM / 64; ++c) {
            const int flat = c * 256 + t;
            const int row = flat >> 2, kb = (flat & 3) * 8;
            gload16(Abf + (size_t)(bm0 + row) * K + k0 + kb, &As[flat * 8]);
        }
        #pragma unroll
        for (int c = 0; c < BN / 64; ++c) {
            const int flat = c * 256 + t;
            const int row = flat >> 2, kb = (flat & 3) * 8;
            gload16(Bhi + (size_t)(bn0 + row) * K + k0 + kb, &Bh[flat * 8]);
            gload16(Blo + (size_t)(bn0 + row) * K + k0 + kb, &Bl[flat * 8]);
        }
        __syncthreads();

        short8 af[FM], bh[FN], bl[FN];
        #pragma unroll
        for (int i = 0; i < FM; ++i)
            af[i] = *(const short8*)&As[(wr * WM + i * 16 + lr) * BK + lk * 8];
        #pragma unroll
        for (int j = 0; j < FN; ++j) {
            bh[j] = *(const short8*)&Bh[(wc * WN + j * 16 + lr) * BK + lk * 8];
            bl[j] = *(const short8*)&Bl[(wc * WN + j * 16 + lr) * BK + lk * 8];
        }
        #pragma unroll
        for (int i = 0; i < FM; ++i)
            #pragma unroll
            for (int j = 0; j < FN; ++j)
                acc[i][j] = __builtin_amdgcn_mfma_f32_16x16x32_bf16(
                    af[i], bh[j], acc[i][j], 0, 0, 0);
        #pragma unroll
        for (int i = 0; i < FM; ++i)
            #pragma unroll
            for (int j = 0; j < FN; ++j)
                acc[i][j] = __builtin_amdgcn_mfma_f32_16x16x32_bf16(
                    af[i], bl[j], acc[i][j], 0, 0, 0);
    }

    // epilogue: D row = (lane>>4)*4 + reg, col = lane&15  [m89/m91-verified]
    #pragma unroll
    for (int i = 0; i < FM; ++i) {
        const int row0 = bm0 + wr * WM + i * 16 + lk * 4;
        #pragma unroll
        for (int j = 0; j < FN; ++j) {
            const int col = bn0 + wc * WN + j * 16 + lr;
            #pragma unroll
            for (int r = 0; r < 4; ++r) {
                const int row = row0 + r;
                float v = acc[i][j][r] + bias[col];
                if (MODE == 0) {
                    v = fmaxf(v, 0.f);
                    outbf[(size_t)row * N + col] = f2bf(v);
                } else {
                    v += resid_x[(size_t)row * N + col]
                       + resid_c[(row & 3) * N + col];
                    outf[(size_t)row * N + col] = v;
                }
            }
        }
    }
}

// ---------------------------------------------------------------------------
extern "C" void kernel_launch(void* const* d_in, const int* in_sizes, int n_in,
                              void* d_out, int out_size, void* d_ws, size_t ws_size,
                              hipStream_t stream)
{
    const float* x     = (const float*)d_in[0];
    const float* qkv_w = (const float*)d_in[1];
    const float* qkv_b = (const float*)d_in[2];
    const float* out_w = (const float*)d_in[3];
    const float* out_b = (const float*)d_in[4];
    const float* ln1_g = (const float*)d_in[5];
    const float* ln1_b = (const float*)d_in[6];
    const float* ff1_w = (const float*)d_in[7];
    const float* ff1_b = (const float*)d_in[8];
    const float* ff2_w = (const float*)d_in[9];
    const float* ff2_b = (const float*)d_in[10];
    const float* ln2_g = (const float*)d_in[11];
    const float* ln2_b = (const float*)d_in[12];

    float* out = (float*)d_out;

    // workspace carve-up (~30 MB)
    float* fws      = (float*)d_ws;
    float* partials = fws;                                   // 4*256*512
    float* mh       = fws + (size_t)4 * NCHUNK * H;          // 2048
    float* vmean    = mh + NB * H;                           // 2048
    float* cvec     = vmean + NB * H;                        // 2048
    u16*   h2bf     = (u16*)(cvec + NB * H);                 // M*H
    u16*   f1bf     = h2bf + (size_t)M * H;                  // M*FF
    u16*   w1hi     = f1bf + (size_t)M * FF;                 // H*FF
    u16*   w1lo     = w1hi + (size_t)H * FF;
    u16*   w2hi     = w1lo + (size_t)H * FF;                 // FF*H
    u16*   w2lo     = w2hi + (size_t)FF * H;

    // weight transpose + split (independent of activations)
    k_wsplit<<<dim3(H / 32, FF / 32), 256, 0, stream>>>(ff1_w, w1hi, w1lo, H, FF);
    k_wsplit<<<dim3(FF / 32, H / 32), 256, 0, stream>>>(ff2_w, w2hi, w2lo, FF, H);

    // attention path (collapsed: SCALE == 0 -> uniform softmax -> mean of V)
    k_ln1_partial<<<NCHUNK, 256, 0, stream>>>(x, ln1_g, ln1_b, partials);
    k_reduce_mean<<<8, 256, 0, stream>>>(partials, mh);
    k_gemv_wave<<<512, 256, 0, stream>>>(mh, qkv_w, qkv_b + 2 * H, vmean,
                                         H, 3 * H, 2 * H);   // Wv slice
    k_gemv_wave<<<512, 256, 0, stream>>>(vmean, out_w, out_b, cvec,
                                         H, H, 0);

    // h2 = LN2(x + c)  -> bf16
    k_ln2<<<M / 4, 256, 0, stream>>>(x, cvec, ln2_g, ln2_b, h2bf);

    // f1 = bf16(relu(h2 @ ff1_w + b1))   [8192,512]@[512,1024]
    gemm_bf16<128, 128, 0><<<dim3(M / 128, FF / 128), 256, 0, stream>>>(
        h2bf, w1hi, w1lo, ff1_b, nullptr, nullptr, nullptr, f1bf, H, FF);

    // out = x + c + f1 @ ff2_w + b2      [8192,1024]@[1024,512]
    gemm_bf16<64, 128, 1><<<dim3(M / 64, H / 128), 256, 0, stream>>>(
        f1bf, w2hi, w2lo, ff2_b, x, cvec, out, nullptr, FF, H);
}